// Round 3
// baseline (22947.926 us; speedup 1.0000x reference)
//
#include <hip/hip_runtime.h>
#include <hip/hip_bf16.h>
#include <hip/hip_cooperative_groups.h>
#include <stdint.h>

namespace cg = cooperative_groups;

// ---------------------------------------------------------------------------
// 2-layer LSTM + linear + CRF NLL on MI355X. ~95 MB workspace plan:
//   - ONE persistent cooperative kernel runs both LSTM layers, layer 1
//     delayed one step (513 grid syncs). No xproj materialization.
//   - Wih fragments in registers (256 VGPR), Whh fragments in 64 KB LDS.
//   - h0 never materialized (2-slab ring); h1_all (64 MB) kept for emis GEMM.
//   - emis kernel -> em (fp32), wave-per-batch CRF.
// Fallback encodes ws_size in the output if the guard fires (absmax - 1552).
// ---------------------------------------------------------------------------

typedef __bf16 bf16x8 __attribute__((ext_vector_type(8)));
typedef float f32x4 __attribute__((ext_vector_type(4)));

__device__ __forceinline__ f32x4 mfma16(bf16x8 a, bf16x8 b, f32x4 c) {
  return __builtin_amdgcn_mfma_f32_16x16x32_bf16(a, b, c, 0, 0, 0);
}

__device__ __forceinline__ unsigned short f2bf(float f) {
  unsigned u = __float_as_uint(f);
  u = u + 0x7fffu + ((u >> 16) & 1u);
  return (unsigned short)(u >> 16);
}
__device__ __forceinline__ float bf2f(unsigned short s) {
  return __uint_as_float(((unsigned)s) << 16);
}
__device__ __forceinline__ float sigf(float x) { return 1.f / (1.f + __expf(-x)); }
__device__ __forceinline__ float tanh_s(float x) {
  float a = fabsf(x);
  float e = __expf(2.f * a);
  float r = 1.f - 2.f / (e + 1.f);   // exp overflow -> inf -> r=1, no NaN
  return copysignf(r, x);
}
__device__ __forceinline__ bf16x8 cvt8(const float* p) {
  float4 a = *(const float4*)p;
  float4 b = *(const float4*)(p + 4);
  union { bf16x8 v; unsigned short u[8]; } r;
  r.u[0] = f2bf(a.x); r.u[1] = f2bf(a.y); r.u[2] = f2bf(a.z); r.u[3] = f2bf(a.w);
  r.u[4] = f2bf(b.x); r.u[5] = f2bf(b.y); r.u[6] = f2bf(b.z); r.u[7] = f2bf(b.w);
  return r.v;
}

// ---------------------------------------------------------------------------
__global__ void fallback_k(float* out, unsigned wsmb) { *out = -(float)wsmb; }

__global__ void cvt_bf16(const float* __restrict__ in, unsigned short* __restrict__ out, int n) {
  int i = (blockIdx.x * 256 + threadIdx.x) * 4;
  if (i < n) {
    float4 v = *(const float4*)(in + i);
    ushort4 o;
    o.x = f2bf(v.x); o.y = f2bf(v.y); o.z = f2bf(v.z); o.w = f2bf(v.w);
    *(ushort4*)(out + i) = o;
  }
}

__global__ void add_vec(const float* __restrict__ a, const float* __restrict__ b,
                        float* __restrict__ o, int n) {
  int i = blockIdx.x * 256 + threadIdx.x;
  if (i < n) o[i] = a[i] + b[i];
}

// ---------------------------------------------------------------------------
// Fused 2-layer persistent scan. 256 blocks x 256 thr, cooperative.
// Blocks 0..127: layer 0 (hidden slice j0 = blk*8). Blocks 128..255: layer 1.
// LDS: Whh B-frags (2 gate-tiles x 32 ksteps, 64 KB). Regs: Wih B-frags.
// Gate tiles: tile0 cols [i(8)|f(8)], tile1 cols [g(8)|o(8)].
// MFMA 16x16x32: A lane m=lane&15 (batch), k=(lane>>4)*8+j; C/D col=lane&15,
// row=(lane>>4)*4+reg (m89-verified mapping).
#define BS(tl, ks) (*(const bf16x8*)&Bsm[((((tl)*32 + (ks)) * 64 + lane)) * 8])

__global__ __launch_bounds__(256, 1) void lstm_fused(
    const float* __restrict__ x,              // [64][512][512] fp32
    const unsigned short* __restrict__ Whh0b, const unsigned short* __restrict__ Wih0b,
    const unsigned short* __restrict__ Whh1b, const unsigned short* __restrict__ Wih1b,
    const float* __restrict__ bias0, const float* __restrict__ bias1,
    unsigned short* __restrict__ h1_all,      // [64][512][1024] bf16
    unsigned short* h0r, unsigned short* h1r) // [2][64][1024] rings
{
  cg::grid_group grid = cg::this_grid();
  __shared__ __align__(16) unsigned short Bsm[32768];   // 64 KB
  const int tid = threadIdx.x;
  const int lane = tid & 63;
  const int w = tid >> 6;            // wave = 16-batch tile
  const int c16 = lane & 15, rg = lane >> 4;
  const bool is1 = blockIdx.x >= 128;
  const int j0 = (is1 ? (int)blockIdx.x - 128 : (int)blockIdx.x) * 8;

  // ---- LDS: Whh B-fragments (k=1024 both layers) ----
  {
    const unsigned short* W = is1 ? Whh1b : Whh0b;
    for (int u = tid; u < 4096; u += 256) {
      int tile = u >> 11;
      int ks = (u >> 6) & 31;
      int ln = u & 63;
      int nn = ln & 15;
      int kb = ks * 32 + (ln >> 4) * 8;
      long row = (long)(tile * 2 + (nn >> 3)) * 1024 + j0 + (nn & 7);
      *(bf16x8*)&Bsm[u * 8] = *(const bf16x8*)(W + row * 1024 + kb);
    }
  }
  // ---- Registers: Wih B-fragments ----
  bf16x8 wf0[32], wf1[32];
  {
    const long ra = (long)(c16 >> 3) * 1024 + j0 + (c16 & 7);        // tile0: i|f row
    const long rb = (long)(2 + (c16 >> 3)) * 1024 + j0 + (c16 & 7);  // tile1: g|o row
    if (is1) {
#pragma unroll
      for (int ks = 0; ks < 32; ++ks) {
        int kb = ks * 32 + rg * 8;
        wf0[ks] = *(const bf16x8*)(Wih1b + ra * 1024 + kb);
        wf1[ks] = *(const bf16x8*)(Wih1b + rb * 1024 + kb);
      }
    } else {
#pragma unroll
      for (int ks = 0; ks < 16; ++ks) {
        int kb = ks * 32 + rg * 8;
        wf0[ks] = *(const bf16x8*)(Wih0b + ra * 512 + kb);
        wf1[ks] = *(const bf16x8*)(Wih0b + rb * 512 + kb);
      }
    }
  }
  unsigned short* ring = is1 ? h1r : h0r;
  // Zero ring slab 1 (read as h[-1]); ws is poisoned each call.
  for (int i = tid; i < 512; i += 256)
    ring[65536 + (i >> 3) * 1024 + j0 + (i & 7)] = 0;

  const int jj = j0 + (c16 & 7);
  const int g01 = c16 >> 3;                 // 0: lane computes (i,g); 1: (f,o)
  const float* bias = is1 ? bias1 : bias0;
  const float bc0 = bias[g01 * 1024 + jj];
  const float bc1 = bias[(2 + g01) * 1024 + jj];
  float cst[4] = {0.f, 0.f, 0.f, 0.f};
  const f32x4 fz = {0.f, 0.f, 0.f, 0.f};

  grid.sync();

  for (int s = 0; s < 513; ++s) {
    const bool active = is1 ? (s >= 1) : (s < 512);
    if (active) {
      const int t = is1 ? s - 1 : s;
      const unsigned short* hprev = ring + ((t & 1) ^ 1) * 65536;
      f32x4 hc0 = fz, hc1 = fz, hd0 = fz, hd1 = fz, e0 = fz, e1 = fz;
      // Whh @ h_prev  (k=1024, LDS B-frags)
      const bf16x8* arow = (const bf16x8*)(hprev + (w * 16 + c16) * 1024 + rg * 8);
#pragma unroll 4
      for (int ks = 0; ks < 32; ks += 2) {
        bf16x8 a0 = arow[ks * 4];
        bf16x8 a1 = arow[(ks + 1) * 4];
        hc0 = mfma16(a0, BS(0, ks), hc0);
        hc1 = mfma16(a0, BS(1, ks), hc1);
        hd0 = mfma16(a1, BS(0, ks + 1), hd0);
        hd1 = mfma16(a1, BS(1, ks + 1), hd1);
      }
      // Wih @ input  (L0: x[t] fp32->bf16 on the fly, k=512; L1: h0[t] ring, k=1024)
      if (!is1) {
        const float* xr = x + ((long)(w * 16 + c16) * 512 + t) * 512 + rg * 8;
#pragma unroll
        for (int ks = 0; ks < 16; ++ks) {
          bf16x8 a = cvt8(xr + ks * 32);
          e0 = mfma16(a, wf0[ks], e0);
          e1 = mfma16(a, wf1[ks], e1);
        }
      } else {
        const bf16x8* ar = (const bf16x8*)(h0r + (t & 1) * 65536 + (w * 16 + c16) * 1024 + rg * 8);
#pragma unroll
        for (int ks = 0; ks < 32; ++ks) {
          bf16x8 a = ar[ks * 4];
          e0 = mfma16(a, wf0[ks], e0);
          e1 = mfma16(a, wf1[ks], e1);
        }
      }
      float p0[4], p1[4], q0[4], q1[4];
#pragma unroll
      for (int r = 0; r < 4; ++r) {
        p0[r] = hc0[r] + hd0[r] + e0[r] + bc0;
        p1[r] = hc1[r] + hd1[r] + e1[r] + bc1;
      }
#pragma unroll
      for (int r = 0; r < 4; ++r) {   // lanes c16<8 receive (f_pre, o_pre)
        q0[r] = __shfl_xor(p0[r], 8);
        q1[r] = __shfl_xor(p1[r], 8);
      }
      if ((c16 & 8) == 0) {
        unsigned short* hn = ring + (t & 1) * 65536;
#pragma unroll
        for (int r = 0; r < 4; ++r) {
          int b = w * 16 + rg * 4 + r;
          float iv = sigf(p0[r]);
          float fv = sigf(q0[r]);
          float gv = tanh_s(p1[r]);
          float ov = sigf(q1[r]);
          float cn = fv * cst[r] + iv * gv;
          cst[r] = cn;
          float hv = ov * tanh_s(cn);
          unsigned short hb = f2bf(hv);
          hn[b * 1024 + jj] = hb;
          if (is1) h1_all[((long)b * 512 + t) * 1024 + jj] = hb;
        }
      }
    }
    grid.sync();
  }
}

// ---------------------------------------------------------------------------
// emissions[m][c] = h1[m][:] . fc_w[c][:] + fc_b[c], c<20 (N padded to 32).
__global__ __launch_bounds__(256) void emis_k(
    const unsigned short* __restrict__ h1, const unsigned short* __restrict__ fcw,
    const float* __restrict__ fcb, float* __restrict__ em) {
  __shared__ __align__(16) unsigned short Bsm[32768];
  const int tid = threadIdx.x;
  const int lane = tid & 63;
  const int w = tid >> 6;
  const int c16 = lane & 15, rg = lane >> 4;
  for (int u = tid; u < 4096; u += 256) {
    int tile = u >> 11;
    int ks = (u >> 6) & 31;
    int ln = u & 63;
    int n = tile * 16 + (ln & 15);
    int kb = ks * 32 + (ln >> 4) * 8;
    if (n < 20) {
      *(bf16x8*)&Bsm[u * 8] = *(const bf16x8*)(fcw + (long)n * 1024 + kb);
    } else {
#pragma unroll
      for (int j = 0; j < 8; ++j) Bsm[u * 8 + j] = 0;
    }
  }
  __syncthreads();
  const long r0 = (long)blockIdx.x * 64;
  const bf16x8* arow = (const bf16x8*)(h1 + (r0 + w * 16 + c16) * 1024 + rg * 8);
  const f32x4 fz = {0.f, 0.f, 0.f, 0.f};
  f32x4 acc0 = fz, acc1 = fz;
#pragma unroll 4
  for (int ks = 0; ks < 32; ++ks) {
    bf16x8 a = arow[ks * 4];
    acc0 = mfma16(a, *(const bf16x8*)&Bsm[(ks * 64 + lane) * 8], acc0);
    acc1 = mfma16(a, *(const bf16x8*)&Bsm[((32 + ks) * 64 + lane) * 8], acc1);
  }
#pragma unroll
  for (int r = 0; r < 4; ++r) {
    long row = r0 + w * 16 + rg * 4 + r;
    em[row * 20 + c16] = acc0[r] + fcb[c16];
    int col1 = 16 + c16;
    if (col1 < 20) em[row * 20 + col1] = acc1[r] + fcb[col1];
  }
}

// ---------------------------------------------------------------------------
// CRF NLL: one wave per batch. Lanes 0..19 hold alpha[j]; 511 serial steps.
__global__ __launch_bounds__(256) void crf_k(
    const float* __restrict__ em, const int* __restrict__ labels,
    const float* __restrict__ startt, const float* __restrict__ endt,
    const float* __restrict__ trans, float* __restrict__ out) {
  const int lane = threadIdx.x & 63;
  const int b = blockIdx.x * 4 + (threadIdx.x >> 6);
  const float NEG = -1e30f;
  const int j = lane;
  const bool act = j < 20;
  float treg[20];
#pragma unroll
  for (int i = 0; i < 20; ++i) treg[i] = act ? trans[i * 20 + j] : 0.f;
  const float* emb = em + (long)b * 512 * 20;
  const int* lab = labels + (long)b * 512;
  float alpha = act ? (startt[j] + emb[j]) : NEG;
  for (int t = 1; t < 512; ++t) {
    float mx = NEG;
#pragma unroll
    for (int i = 0; i < 20; ++i) {
      float v = __shfl(alpha, i) + treg[i];
      mx = fmaxf(mx, v);
    }
    float s = 0.f;
#pragma unroll
    for (int i = 0; i < 20; ++i) {
      float v = __shfl(alpha, i) + treg[i];
      s += __expf(v - mx);
    }
    bool m = lab[t] != -1;
    float na = emb[t * 20 + (act ? j : 0)] + mx + __logf(s);
    if (act && m) alpha = na;
  }
  float v = act ? (alpha + endt[j]) : NEG;
  float mx = v;
#pragma unroll
  for (int o = 32; o > 0; o >>= 1) mx = fmaxf(mx, __shfl_xor(mx, o));
  float s = act ? __expf(v - mx) : 0.f;
#pragma unroll
  for (int o = 32; o > 0; o >>= 1) s += __shfl_xor(s, o);
  float logZ = mx + __logf(s);
  // score terms, parallel over t across lanes
  float part = 0.f;
  int cntm = 0;
  for (int t = lane; t < 512; t += 64) cntm += (lab[t] != -1) ? 1 : 0;
  for (int t = 1 + lane; t < 512; t += 64) {
    int tg = lab[t];
    if (tg != -1) {
      int tp = lab[t - 1];
      int tgc = min(max(tg, 0), 19);
      int tpc = min(max(tp, 0), 19);
      part += trans[tpc * 20 + tgc] + emb[t * 20 + tgc];
    }
  }
#pragma unroll
  for (int o = 32; o > 0; o >>= 1) {
    part += __shfl_xor(part, o);
    cntm += __shfl_xor(cntm, o);
  }
  if (lane == 0) {
    int t0c = min(max(lab[0], 0), 19);
    float score = startt[t0c] + emb[t0c] + part;
    int last = max(cntm - 1, 0);
    int tlc = min(max(lab[last], 0), 19);
    score += endt[tlc];
    float llh = score - logZ;
    atomicAdd(out, llh * (-1.f / 64.f));
  }
}

// ---------------------------------------------------------------------------
extern "C" void kernel_launch(void* const* d_in, const int* in_sizes, int n_in,
                              void* d_out, int out_size, void* d_ws, size_t ws_size,
                              hipStream_t stream) {
  const float* x      = (const float*)d_in[0];
  const int* labels   = (const int*)d_in[1];
  // d_in[2] = lengths (mask comes from labels per reference)
  const float* Wih0   = (const float*)d_in[3];
  const float* Whh0   = (const float*)d_in[4];
  const float* bih0   = (const float*)d_in[5];
  const float* bhh0   = (const float*)d_in[6];
  const float* Wih1   = (const float*)d_in[7];
  const float* Whh1   = (const float*)d_in[8];
  const float* bih1   = (const float*)d_in[9];
  const float* bhh1   = (const float*)d_in[10];
  const float* fcw    = (const float*)d_in[11];
  const float* fcb    = (const float*)d_in[12];
  const float* startt = (const float*)d_in[13];
  const float* endt   = (const float*)d_in[14];
  const float* trans  = (const float*)d_in[15];
  float* out = (float*)d_out;

  char* ws = (char*)d_ws;
  size_t off = 0;
  auto alloc = [&](size_t bytes) -> void* {
    void* p = ws + off;
    off = (off + bytes + 255) & ~(size_t)255;
    return p;
  };
  unsigned short* h1_all = (unsigned short*)alloc(33554432ull * 2);  // 64 MB
  unsigned short* Whh0_b = (unsigned short*)alloc(4194304ull * 2);   // 8 MB
  unsigned short* Wih0_b = (unsigned short*)alloc(2097152ull * 2);   // 4 MB
  unsigned short* Whh1_b = (unsigned short*)alloc(4194304ull * 2);   // 8 MB
  unsigned short* Wih1_b = (unsigned short*)alloc(4194304ull * 2);   // 8 MB
  unsigned short* fcw_b  = (unsigned short*)alloc(20480ull * 2);
  float* bias0           = (float*)alloc(4096 * 4);
  float* bias1           = (float*)alloc(4096 * 4);
  unsigned short* h0r    = (unsigned short*)alloc(131072ull * 2);    // 2 slabs
  unsigned short* h1r    = (unsigned short*)alloc(131072ull * 2);
  float* em              = (float*)alloc(32768ull * 20 * 4);         // 2.6 MB

  if (off > ws_size) {   // clean fail; absmax-1552 encodes ws_size in MB
    unsigned wsmb = (unsigned)(ws_size >> 20);
    fallback_k<<<1, 1, 0, stream>>>(out, wsmb);
    return;
  }

  hipMemsetAsync(d_out, 0, sizeof(float), stream);

  cvt_bf16<<<4096, 256, 0, stream>>>(Whh0, Whh0_b, 4194304);
  cvt_bf16<<<2048, 256, 0, stream>>>(Wih0, Wih0_b, 2097152);
  cvt_bf16<<<4096, 256, 0, stream>>>(Whh1, Whh1_b, 4194304);
  cvt_bf16<<<4096, 256, 0, stream>>>(Wih1, Wih1_b, 4194304);
  cvt_bf16<<<20, 256, 0, stream>>>(fcw, fcw_b, 20480);
  add_vec<<<16, 256, 0, stream>>>(bih0, bhh0, bias0, 4096);
  add_vec<<<16, 256, 0, stream>>>(bih1, bhh1, bias1, 4096);

  {
    void* args[] = {(void*)&x, (void*)&Whh0_b, (void*)&Wih0_b, (void*)&Whh1_b,
                    (void*)&Wih1_b, (void*)&bias0, (void*)&bias1,
                    (void*)&h1_all, (void*)&h0r, (void*)&h1r};
    hipLaunchCooperativeKernel((void*)lstm_fused, dim3(256), dim3(256), args, 0, stream);
  }
  emis_k<<<512, 256, 0, stream>>>(h1_all, fcw_b, fcb, em);
  crf_k<<<16, 256, 0, stream>>>(em, labels, startt, endt, trans, out);
}

// Round 4
// 19608.887 us; speedup vs baseline: 1.1703x; 1.1703x over previous
//
#include <hip/hip_runtime.h>
#include <hip/hip_bf16.h>
#include <hip/hip_cooperative_groups.h>
#include <stdint.h>

// ---------------------------------------------------------------------------
// 2-layer LSTM + linear + CRF NLL on MI355X.
// Round 4: custom fence-free grid barrier (agent-scope relaxed atomics through
// LLC) replaces cg::grid.sync() (measured 44 us/slot). W-as-A-operand MFMA
// layout makes the cell update lane-local (no half-wave idle, no gate shuffle).
// Blocks 0..127 = layer 0 (8 hidden units each), 128..255 = layer 1 (lag 1).
// Whh A-frags in 64 KB LDS; Wih A-frags in registers; h rings ping-pong via
// LLC-coherent atomic stores/loads (per-XCD L2 never holds cross-block data).
// ---------------------------------------------------------------------------

namespace cg = cooperative_groups;

typedef __bf16 bf16x8 __attribute__((ext_vector_type(8)));
typedef float f32x4 __attribute__((ext_vector_type(4)));

__device__ __forceinline__ f32x4 mfma16(bf16x8 a, bf16x8 b, f32x4 c) {
  return __builtin_amdgcn_mfma_f32_16x16x32_bf16(a, b, c, 0, 0, 0);
}

__device__ __forceinline__ unsigned short f2bf(float f) {
  unsigned u = __float_as_uint(f);
  u = u + 0x7fffu + ((u >> 16) & 1u);
  return (unsigned short)(u >> 16);
}
__device__ __forceinline__ float sigf(float x) { return 1.f / (1.f + __expf(-x)); }
__device__ __forceinline__ float tanh_s(float x) {
  float a = fabsf(x);
  float e = __expf(2.f * a);
  float r = 1.f - 2.f / (e + 1.f);
  return copysignf(r, x);
}
__device__ __forceinline__ bf16x8 cvt8(const float* p) {
  float4 a = *(const float4*)p;
  float4 b = *(const float4*)(p + 4);
  union { bf16x8 v; unsigned short u[8]; } r;
  r.u[0] = f2bf(a.x); r.u[1] = f2bf(a.y); r.u[2] = f2bf(a.z); r.u[3] = f2bf(a.w);
  r.u[4] = f2bf(b.x); r.u[5] = f2bf(b.y); r.u[6] = f2bf(b.z); r.u[7] = f2bf(b.w);
  return r.v;
}

// ---- LLC-coherent (agent-scope, relaxed) primitives ----
__device__ __forceinline__ unsigned ald32(const unsigned* p) {
  return __hip_atomic_load(p, __ATOMIC_RELAXED, __HIP_MEMORY_SCOPE_AGENT);
}
__device__ __forceinline__ void aadd32(unsigned* p) {
  __hip_atomic_fetch_add(p, 1u, __ATOMIC_RELAXED, __HIP_MEMORY_SCOPE_AGENT);
}
__device__ __forceinline__ unsigned long long ald64(const void* p) {
  return __hip_atomic_load((const unsigned long long*)p, __ATOMIC_RELAXED,
                           __HIP_MEMORY_SCOPE_AGENT);
}
__device__ __forceinline__ void ast32(void* p, unsigned v) {
  __hip_atomic_store((unsigned*)p, v, __ATOMIC_RELAXED, __HIP_MEMORY_SCOPE_AGENT);
}
__device__ __forceinline__ void ast64(void* p, unsigned long long v) {
  __hip_atomic_store((unsigned long long*)p, v, __ATOMIC_RELAXED,
                     __HIP_MEMORY_SCOPE_AGENT);
}
__device__ __forceinline__ bf16x8 ldh(const unsigned short* p) {  // 16B via 2x8B LLC loads
  union { bf16x8 v; unsigned long long q[2]; } u;
  u.q[0] = ald64(p);
  u.q[1] = ald64(p + 4);
  return u.v;
}

// ---------------------------------------------------------------------------
__global__ void fallback_k(float* out, unsigned wsmb) { *out = -(float)wsmb; }

__global__ void cvt_bf16(const float* __restrict__ in, unsigned short* __restrict__ out, int n) {
  int i = (blockIdx.x * 256 + threadIdx.x) * 4;
  if (i < n) {
    float4 v = *(const float4*)(in + i);
    ushort4 o;
    o.x = f2bf(v.x); o.y = f2bf(v.y); o.z = f2bf(v.z); o.w = f2bf(v.w);
    *(ushort4*)(out + i) = o;
  }
}

__global__ void add_vec(const float* __restrict__ a, const float* __restrict__ b,
                        float* __restrict__ o, int n) {
  int i = blockIdx.x * 256 + threadIdx.x;
  if (i < n) o[i] = a[i] + b[i];
}

// ---------------------------------------------------------------------------
// Fused 2-layer persistent scan, custom barriers.
// MFMA roles: A = W rows (m = jj*4 + gate, so lane (c16,rg) after D holds all
// 4 gates (reg r) of hidden unit j0+mi*4+rg for batch w*16+c16), B = h / x.
// A-frag: lane m=lane&15, k=(lane>>4)*8+i. B-frag: lane n=lane&15 (batch),
// k=(lane>>4)*8+i. C/D: col(n)=lane&15, row(m)=(lane>>4)*4+reg.
#define BS(mi, ks) (*(const bf16x8*)&Bsm[(((mi)*2048 + (ks)*64 + lane)) * 8])

__global__ __launch_bounds__(256, 1) void lstm_fused(
    const float* __restrict__ x,              // [64][512][512] fp32
    const unsigned short* __restrict__ Whh0b, const unsigned short* __restrict__ Wih0b,
    const unsigned short* __restrict__ Whh1b, const unsigned short* __restrict__ Wih1b,
    const float* __restrict__ bias0, const float* __restrict__ bias1,
    unsigned short* __restrict__ h1_all,      // [64][512][1024] bf16
    unsigned short* h0r, unsigned short* h1r, // [2][64][1024] rings (LLC-coherent)
    unsigned* c0, unsigned* c1)
{
  __shared__ __align__(16) unsigned short Bsm[32768];   // 64 KB Whh A-frags
  const int tid = threadIdx.x;
  const int lane = tid & 63;
  const int w = tid >> 6;            // wave = 16-batch tile
  const int c16 = lane & 15, rg = lane >> 4;
  const bool is1 = blockIdx.x >= 128;
  const int j0 = (is1 ? (int)blockIdx.x - 128 : (int)blockIdx.x) * 8;

  // ---- LDS: Whh A-frags. unit u = mi*2048 + ks*64 + ln; ln is the MFMA lane:
  // m=ln&15 -> (gate=m&3, jj=m>>2); k = ks*32 + (ln>>4)*8.
  {
    const unsigned short* W = is1 ? Whh1b : Whh0b;
    for (int u = tid; u < 4096; u += 256) {
      int mi = u >> 11;
      int ks = (u >> 6) & 31;
      int ln = u & 63;
      int m = ln & 15;
      long row = (long)(m & 3) * 1024 + j0 + mi * 4 + (m >> 2);
      *(bf16x8*)&Bsm[u * 8] = *(const bf16x8*)(W + row * 1024 + ks * 32 + (ln >> 4) * 8);
    }
  }
  // ---- Registers: Wih A-frags (L0: K=512 -> 2x16; L1: K=1024 -> 2x32) ----
  bf16x8 wf[2][32];
  {
    const int g = c16 & 3, jj = c16 >> 2;
    if (is1) {
#pragma unroll
      for (int mi = 0; mi < 2; ++mi) {
        long row = (long)g * 1024 + j0 + mi * 4 + jj;
#pragma unroll
        for (int ks = 0; ks < 32; ++ks)
          wf[mi][ks] = *(const bf16x8*)(Wih1b + row * 1024 + ks * 32 + rg * 8);
      }
    } else {
#pragma unroll
      for (int mi = 0; mi < 2; ++mi) {
        long row = (long)g * 1024 + j0 + mi * 4 + jj;
#pragma unroll
        for (int ks = 0; ks < 16; ++ks)
          wf[mi][ks] = *(const bf16x8*)(Wih0b + row * 512 + ks * 32 + rg * 8);
      }
    }
  }
  // ---- biases: bs[mi][r] = bias[r*1024 + j] ----
  const float* bias = is1 ? bias1 : bias0;
  float bs[2][4];
#pragma unroll
  for (int mi = 0; mi < 2; ++mi)
#pragma unroll
    for (int r = 0; r < 4; ++r) bs[mi][r] = bias[r * 1024 + j0 + mi * 4 + rg];

  // ---- zero own slice of slab 1 of own ring (read as h[-1]), LLC stores ----
  unsigned short* ring = is1 ? h1r : h0r;
  if (tid < 128) ast64(ring + 65536 + (tid >> 1) * 1024 + j0 + (tid & 1) * 4, 0ull);
  __syncthreads();                       // drains vmcnt for all waves
  if (tid == 0) aadd32(is1 ? c1 : c0);   // zero-epoch arrival

  const int boff = (w * 16 + c16) * 1024;
  const int koffbase = rg * 8;
  float cst[2] = {0.f, 0.f};
  const f32x4 fz = {0.f, 0.f, 0.f, 0.f};

  for (int s = 0; s < 512; ++s) {
    // L0: prefetch x frags (barrier-independent)
    bf16x8 xa[16];
    if (!is1) {
      const float* xp = x + ((long)(w * 16 + c16) * 512 + s) * 512 + koffbase;
#pragma unroll
      for (int ks = 0; ks < 16; ++ks) xa[ks] = cvt8(xp + ks * 32);
    }
    // ---- wait ----
    if (tid == 0) {
      if (!is1) {
        while (ald32(c0) < 128u * (s + 1)) __builtin_amdgcn_s_sleep(2);
        if (s >= 2)
          while (ald32(c1) < 128u * s) __builtin_amdgcn_s_sleep(2);
      } else {
        while (ald32(c1) < 128u * (s + 1)) __builtin_amdgcn_s_sleep(2);
        while (ald32(c0) < 128u * (s + 2)) __builtin_amdgcn_s_sleep(2);
      }
    }
    __syncthreads();
    __atomic_signal_fence(__ATOMIC_ACQ_REL);   // compiler reorder guard

    f32x4 aW0 = fz, aW1 = fz, aI0 = fz, aI1 = fz;
    const unsigned short* hprev = ring + ((s + 1) & 1) * 65536 + boff + koffbase;
    if (!is1) {
#pragma unroll 8
      for (int ks = 0; ks < 32; ++ks) {
        bf16x8 hb = ldh(hprev + ks * 32);
        aW0 = mfma16(BS(0, ks), hb, aW0);
        aW1 = mfma16(BS(1, ks), hb, aW1);
      }
#pragma unroll
      for (int ks = 0; ks < 16; ++ks) {
        aI0 = mfma16(wf[0][ks], xa[ks], aI0);
        aI1 = mfma16(wf[1][ks], xa[ks], aI1);
      }
    } else {
      const unsigned short* h0p = h0r + (s & 1) * 65536 + boff + koffbase;
#pragma unroll 8
      for (int ks = 0; ks < 32; ++ks) {
        bf16x8 hb = ldh(hprev + ks * 32);
        bf16x8 h0b = ldh(h0p + ks * 32);
        aW0 = mfma16(BS(0, ks), hb, aW0);
        aW1 = mfma16(BS(1, ks), hb, aW1);
        aI0 = mfma16(wf[0][ks], h0b, aI0);
        aI1 = mfma16(wf[1][ks], h0b, aI1);
      }
    }
    // ---- gates (lane-local), cell update, packed 32-bit LLC store ----
    unsigned short* rout = ring + (s & 1) * 65536;
    const int b = w * 16 + c16;
#pragma unroll
    for (int mi = 0; mi < 2; ++mi) {
      float iv = sigf(aW0[0] * 0.f + (mi ? aW1[0] + aI1[0] : aW0[0] + aI0[0]) + bs[mi][0]);
      float fv = sigf((mi ? aW1[1] + aI1[1] : aW0[1] + aI0[1]) + bs[mi][1]);
      float gv = tanh_s((mi ? aW1[2] + aI1[2] : aW0[2] + aI0[2]) + bs[mi][2]);
      float ov = sigf((mi ? aW1[3] + aI1[3] : aW0[3] + aI0[3]) + bs[mi][3]);
      float cn = fv * cst[mi] + iv * gv;
      cst[mi] = cn;
      float hv = ov * tanh_s(cn);
      unsigned hu = f2bf(hv);
      int j = j0 + mi * 4 + rg;
      // pack with rg-parity partner (lane ^ 16): even rg stores (even j low)
      unsigned pu = (unsigned)__shfl_xor((int)hu, 16);
      if ((rg & 1) == 0) ast32(rout + b * 1024 + j, hu | (pu << 16));
      if (is1) h1_all[((long)b * 512 + s) * 1024 + j] = (unsigned short)hu;
    }
    __syncthreads();                         // drain all waves' LLC stores
    if (tid == 0) aadd32(is1 ? c1 : c0);     // slot arrival
  }
}

// ---------------------------------------------------------------------------
// emissions[m][c] = h1[m][:] . fc_w[c][:] + fc_b[c], c<20 (N padded to 32).
__global__ __launch_bounds__(256) void emis_k(
    const unsigned short* __restrict__ h1, const unsigned short* __restrict__ fcw,
    const float* __restrict__ fcb, float* __restrict__ em) {
  __shared__ __align__(16) unsigned short Bsm[32768];
  const int tid = threadIdx.x;
  const int lane = tid & 63;
  const int w = tid >> 6;
  const int c16 = lane & 15, rg = lane >> 4;
  for (int u = tid; u < 4096; u += 256) {
    int tile = u >> 11;
    int ks = (u >> 6) & 31;
    int ln = u & 63;
    int n = tile * 16 + (ln & 15);
    int kb = ks * 32 + (ln >> 4) * 8;
    if (n < 20) {
      *(bf16x8*)&Bsm[u * 8] = *(const bf16x8*)(fcw + (long)n * 1024 + kb);
    } else {
#pragma unroll
      for (int j = 0; j < 8; ++j) Bsm[u * 8 + j] = 0;
    }
  }
  __syncthreads();
  const long r0 = (long)blockIdx.x * 64;
  const bf16x8* arow = (const bf16x8*)(h1 + (r0 + w * 16 + c16) * 1024 + rg * 8);
  const f32x4 fz = {0.f, 0.f, 0.f, 0.f};
  f32x4 acc0 = fz, acc1 = fz;
#pragma unroll 4
  for (int ks = 0; ks < 32; ++ks) {
    bf16x8 a = arow[ks * 4];
    acc0 = mfma16(a, *(const bf16x8*)&Bsm[(ks * 64 + lane) * 8], acc0);
    acc1 = mfma16(a, *(const bf16x8*)&Bsm[((32 + ks) * 64 + lane) * 8], acc1);
  }
#pragma unroll
  for (int r = 0; r < 4; ++r) {
    long row = r0 + w * 16 + rg * 4 + r;
    em[row * 20 + c16] = acc0[r] + fcb[c16];
    int col1 = 16 + c16;
    if (col1 < 20) em[row * 20 + col1] = acc1[r] + fcb[col1];
  }
}

// ---------------------------------------------------------------------------
// CRF NLL: one wave per batch. Lanes 0..19 hold alpha[j]; 511 serial steps.
__global__ __launch_bounds__(256) void crf_k(
    const float* __restrict__ em, const int* __restrict__ labels,
    const float* __restrict__ startt, const float* __restrict__ endt,
    const float* __restrict__ trans, float* __restrict__ out) {
  const int lane = threadIdx.x & 63;
  const int b = blockIdx.x * 4 + (threadIdx.x >> 6);
  const float NEG = -1e30f;
  const int j = lane;
  const bool act = j < 20;
  float treg[20];
#pragma unroll
  for (int i = 0; i < 20; ++i) treg[i] = act ? trans[i * 20 + j] : 0.f;
  const float* emb = em + (long)b * 512 * 20;
  const int* lab = labels + (long)b * 512;
  float alpha = act ? (startt[j] + emb[j]) : NEG;
  for (int t = 1; t < 512; ++t) {
    float mx = NEG;
#pragma unroll
    for (int i = 0; i < 20; ++i) {
      float v = __shfl(alpha, i) + treg[i];
      mx = fmaxf(mx, v);
    }
    float s = 0.f;
#pragma unroll
    for (int i = 0; i < 20; ++i) {
      float v = __shfl(alpha, i) + treg[i];
      s += __expf(v - mx);
    }
    bool m = lab[t] != -1;
    float na = emb[t * 20 + (act ? j : 0)] + mx + __logf(s);
    if (act && m) alpha = na;
  }
  float v = act ? (alpha + endt[j]) : NEG;
  float mx = v;
#pragma unroll
  for (int o = 32; o > 0; o >>= 1) mx = fmaxf(mx, __shfl_xor(mx, o));
  float s = act ? __expf(v - mx) : 0.f;
#pragma unroll
  for (int o = 32; o > 0; o >>= 1) s += __shfl_xor(s, o);
  float logZ = mx + __logf(s);
  float part = 0.f;
  int cntm = 0;
  for (int t = lane; t < 512; t += 64) cntm += (lab[t] != -1) ? 1 : 0;
  for (int t = 1 + lane; t < 512; t += 64) {
    int tg = lab[t];
    if (tg != -1) {
      int tp = lab[t - 1];
      int tgc = min(max(tg, 0), 19);
      int tpc = min(max(tp, 0), 19);
      part += trans[tpc * 20 + tgc] + emb[t * 20 + tgc];
    }
  }
#pragma unroll
  for (int o = 32; o > 0; o >>= 1) {
    part += __shfl_xor(part, o);
    cntm += __shfl_xor(cntm, o);
  }
  if (lane == 0) {
    int t0c = min(max(lab[0], 0), 19);
    float score = startt[t0c] + emb[t0c] + part;
    int last = max(cntm - 1, 0);
    int tlc = min(max(lab[last], 0), 19);
    score += endt[tlc];
    float llh = score - logZ;
    atomicAdd(out, llh * (-1.f / 64.f));
  }
}

// ---------------------------------------------------------------------------
extern "C" void kernel_launch(void* const* d_in, const int* in_sizes, int n_in,
                              void* d_out, int out_size, void* d_ws, size_t ws_size,
                              hipStream_t stream) {
  const float* x      = (const float*)d_in[0];
  const int* labels   = (const int*)d_in[1];
  const float* Wih0   = (const float*)d_in[3];
  const float* Whh0   = (const float*)d_in[4];
  const float* bih0   = (const float*)d_in[5];
  const float* bhh0   = (const float*)d_in[6];
  const float* Wih1   = (const float*)d_in[7];
  const float* Whh1   = (const float*)d_in[8];
  const float* bih1   = (const float*)d_in[9];
  const float* bhh1   = (const float*)d_in[10];
  const float* fcw    = (const float*)d_in[11];
  const float* fcb    = (const float*)d_in[12];
  const float* startt = (const float*)d_in[13];
  const float* endt   = (const float*)d_in[14];
  const float* trans  = (const float*)d_in[15];
  float* out = (float*)d_out;

  char* ws = (char*)d_ws;
  size_t off = 0;
  auto alloc = [&](size_t bytes) -> void* {
    void* p = ws + off;
    off = (off + bytes + 255) & ~(size_t)255;
    return p;
  };
  unsigned short* h1_all = (unsigned short*)alloc(33554432ull * 2);  // 64 MB
  unsigned short* Whh0_b = (unsigned short*)alloc(4194304ull * 2);
  unsigned short* Wih0_b = (unsigned short*)alloc(2097152ull * 2);
  unsigned short* Whh1_b = (unsigned short*)alloc(4194304ull * 2);
  unsigned short* Wih1_b = (unsigned short*)alloc(4194304ull * 2);
  unsigned short* fcw_b  = (unsigned short*)alloc(20480ull * 2);
  float* bias0           = (float*)alloc(4096 * 4);
  float* bias1           = (float*)alloc(4096 * 4);
  unsigned short* h0r    = (unsigned short*)alloc(131072ull * 2);
  unsigned short* h1r    = (unsigned short*)alloc(131072ull * 2);
  float* em              = (float*)alloc(32768ull * 20 * 4);
  unsigned* cnts         = (unsigned*)alloc(256);
  unsigned* c0 = cnts;
  unsigned* c1 = cnts + 32;   // separate cacheline

  if (off > ws_size) {
    unsigned wsmb = (unsigned)(ws_size >> 20);
    fallback_k<<<1, 1, 0, stream>>>(out, wsmb);
    return;
  }

  hipMemsetAsync(cnts, 0, 256, stream);
  hipMemsetAsync(d_out, 0, sizeof(float), stream);

  cvt_bf16<<<4096, 256, 0, stream>>>(Whh0, Whh0_b, 4194304);
  cvt_bf16<<<2048, 256, 0, stream>>>(Wih0, Wih0_b, 2097152);
  cvt_bf16<<<4096, 256, 0, stream>>>(Whh1, Whh1_b, 4194304);
  cvt_bf16<<<4096, 256, 0, stream>>>(Wih1, Wih1_b, 4194304);
  cvt_bf16<<<20, 256, 0, stream>>>(fcw, fcw_b, 20480);
  add_vec<<<16, 256, 0, stream>>>(bih0, bhh0, bias0, 4096);
  add_vec<<<16, 256, 0, stream>>>(bih1, bhh1, bias1, 4096);

  {
    void* args[] = {(void*)&x, (void*)&Whh0_b, (void*)&Wih0_b, (void*)&Whh1_b,
                    (void*)&Wih1_b, (void*)&bias0, (void*)&bias1,
                    (void*)&h1_all, (void*)&h0r, (void*)&h1r,
                    (void*)&c0, (void*)&c1};
    hipLaunchCooperativeKernel((void*)lstm_fused, dim3(256), dim3(256), args, 0, stream);
  }
  emis_k<<<512, 256, 0, stream>>>(h1_all, fcw_b, fcb, em);
  crf_k<<<16, 256, 0, stream>>>(em, labels, startt, endt, trans, out);
}